// Round 8
// baseline (119.820 us; speedup 1.0000x reference)
//
#include <hip/hip_runtime.h>
#include <math.h>

#define HX 48
#define WX 48
#define OMC 216
#define HY 96
#define WY 96

typedef __attribute__((ext_vector_type(8))) short bf16x8;
typedef __attribute__((ext_vector_type(4))) float f32x4;

__device__ inline unsigned short f2bf(float f) {
  unsigned u = __float_as_uint(f);
  return (unsigned short)((u + 0x7fffu + ((u >> 16) & 1u)) >> 16);  // RNE
}
__device__ inline unsigned pk2(float a, float b) {
  return (unsigned)f2bf(a) | ((unsigned)f2bf(b) << 16);
}

// ws layout (floats):
//  om  @ 0          : 1,990,656
//  ap2 @ 1,990,656  :    73,728   (147,456 bf16: conv A-frags [3p][6s][16m][64l][8])
//  ap1 @ 2,064,384  :    18,432   ( 36,864 bf16: deform A-frags [3p][6s][4w][64l][8])
//  yt  @ 2,082,816  : 2,359,296
//  shr @ 4,442,112  : 7,962,624   (pc [3*576*4096] first, then rs reuses it)
//  pt  @ 12,404,736 : 7,077,888
//  total 19,482,624 f ~= 77.9 MiB

// ---------- prep: pack bf16 MFMA A-fragments for both GEMMs ----------
__global__ __launch_bounds__(256) void prep_pack_kernel(
    const float* __restrict__ w_om, const float* __restrict__ w_dc,
    unsigned short* __restrict__ ap2, unsigned short* __restrict__ ap1) {
  int idx = blockIdx.x * 256 + threadIdx.x;   // 0..184319
  if (idx < 147456) {
    int j = idx & 7;
    int tmp = idx >> 3;
    int l = tmp & 63; tmp >>= 6;
    int m = tmp & 15; tmp >>= 4;              // 0..17
    int s = tmp % 6, p = tmp / 6;
    int oc = m * 16 + (l & 15);
    int kk = s * 32 + (l >> 4) * 8 + j;       // 0..191
    int tap = kk >> 6, c = kk & 63;
    int k = p * 3 + tap;
    ap2[idx] = (oc < OMC) ? f2bf(w_om[oc * 576 + c * 9 + k]) : (unsigned short)0;
  } else {
    int i2 = idx - 147456;                    // < 36864
    int j = i2 & 7;
    int tmp = i2 >> 3;
    int l = tmp & 63; tmp >>= 6;
    int w = tmp & 3; tmp >>= 2;               // 0..17
    int s = tmp % 6, p = tmp / 6;
    int oc = w * 16 + (l & 15);
    int kk = s * 32 + (l >> 4) * 8 + j;
    int tap = kk >> 6, c = kk & 63;
    ap1[i2] = f2bf(w_dc[oc * 576 + c * 9 + p * 3 + tap]);
  }
}

// ---------- y[b][c][p] -> yt[b][p][c] (fp32) ----------
__global__ __launch_bounds__(256) void ytr_kernel(const float* __restrict__ y,
                                                  float* __restrict__ yt) {
  __shared__ float tile[64][65];
  int blk = blockIdx.x;  // 576 = 4b * 144
  int b = blk / 144;
  int p0 = (blk % 144) * 64;
  int t = threadIdx.x;
  int pl = t & 63;
  int cb = t >> 6;
#pragma unroll
  for (int i = 0; i < 16; ++i) {
    int c = cb * 16 + i;
    tile[c][pl] = y[((size_t)(b * 64 + c)) * 9216 + p0 + pl];
  }
  __syncthreads();
  int cw = t & 63;
  int pb = t >> 6;
#pragma unroll
  for (int i = 0; i < 16; ++i) {
    int p = pb * 16 + i;
    yt[((size_t)(b * 9216 + p0 + p)) * 64 + cw] = tile[cw][p];
  }
}

// ---------- conv K-part via MFMA: 256oc x 16px, taps 3p..3p+2 ----------
__global__ __launch_bounds__(256) void conv_mfma_kernel(
    const float* __restrict__ x, const unsigned short* __restrict__ ap2,
    float* __restrict__ pc) {
  __shared__ unsigned short sB[3][16][72];    // 6912 B, [tap][px][c]
  int t = threadIdx.x;
  int bid = blockIdx.x;                       // 1728
  int logical = (bid & 7) * 216 + (bid >> 3); // bijective XCD swizzle
  int p = logical / 576;
  int tile576 = logical % 576;
  int b = tile576 / 144;
  int tl = tile576 % 144;
  int h0 = (tl / 12) * 4;
  int w0 = (tl % 12) * 4;
  int k0 = p * 3;
  int s_ic = t >> 2;
  int s_row = t & 3;
  const float* xp = x + (size_t)b * 64 * 2304 + (size_t)s_ic * 2304;

#pragma unroll
  for (int tap = 0; tap < 3; ++tap) {
    int k = k0 + tap;
    int dy = k / 3 - 1, dx = k % 3 - 1;
    int hh = h0 + s_row + dy;
    int ww = w0 + dx;
    bool hv = (unsigned)hh < (unsigned)HX;
    int hc = min(max(hh, 0), HX - 1);
    const float* xr = xp + hc * WX;
#pragma unroll
    for (int j = 0; j < 4; ++j) {
      int wcj = min(max(ww + j, 0), WX - 1);
      float v = xr[wcj] * ((hv && (unsigned)(ww + j) < (unsigned)WX) ? 1.f : 0.f);
      sB[tap][s_row * 4 + j][s_ic] = f2bf(v);
    }
  }
  __syncthreads();

  int w = t >> 6;
  int l = t & 63;
  int lr = l & 15;
  int lg = l >> 4;
  f32x4 acc[4] = {};
#pragma unroll
  for (int s = 0; s < 6; ++s) {
    int tap = s >> 1;
    int c0 = (s & 1) * 32;
    bf16x8 bv = *(const bf16x8*)&sB[tap][lr][c0 + lg * 8];
#pragma unroll
    for (int m = 0; m < 4; ++m) {
      bf16x8 av = *(const bf16x8*)(ap2 +
          (size_t)((((p * 6 + s) * 16) + w * 4 + m) * 64 + l) * 8);
      acc[m] = __builtin_amdgcn_mfma_f32_16x16x32_bf16(av, bv, acc[m], 0, 0, 0);
    }
  }
  float* pb = pc + (size_t)(p * 576 + tile576) * 4096;
#pragma unroll
  for (int m = 0; m < 4; ++m) {
#pragma unroll
    for (int i = 0; i < 4; ++i) {
      int oc = (w * 4 + m) * 16 + lg * 4 + i;
      pb[oc * 16 + lr] = acc[m][i];
    }
  }
}

// ---------- creduce: sum 3 conv parts + bias -> om (fp32) ----------
__global__ __launch_bounds__(256) void creduce_kernel(
    const float* __restrict__ pc, const float* __restrict__ bom,
    float* __restrict__ om) {
  int tile = blockIdx.x;  // 0..575
  int b = tile / 144;
  int tl = tile % 144;
  int h0 = (tl / 12) * 4;
  int w0 = (tl % 12) * 4;
  int n = threadIdx.x;    // oc
  if (n >= OMC) return;
  const float4* p0 = (const float4*)(pc + (size_t)(0 * 576 + tile) * 4096);
  const float4* p1 = (const float4*)(pc + (size_t)(1 * 576 + tile) * 4096);
  const float4* p2 = (const float4*)(pc + (size_t)(2 * 576 + tile) * 4096);
  float bv = bom[n];
#pragma unroll
  for (int q = 0; q < 4; ++q) {   // px row
    int j = n * 4 + q;
    float4 a = p0[j], c = p1[j], d = p2[j];
    float4 o;
    o.x = a.x + c.x + d.x + bv;
    o.y = a.y + c.y + d.y + bv;
    o.z = a.z + c.z + d.z + bv;
    o.w = a.w + c.w + d.w + bv;
    *(float4*)&om[((size_t)(b * OMC + n)) * 2304 + (h0 + q) * WX + w0] = o;
  }
}

// ---------- resize: LDS-staged, one block per (b,k,g) ----------
__global__ __launch_bounds__(256) void resize_kernel(const float* __restrict__ om,
                                                     float* __restrict__ rs) {
  __shared__ float sC[3][2304];
  int blk = blockIdx.x;         // 288 = b*72 + k*8 + g
  int g = blk % 8;
  int k = (blk / 8) % 9;
  int b = blk / 72;
  const float* omb = om + (size_t)b * OMC * 2304;
  const float* s0 = omb + (size_t)(g * 18 + k * 2) * 2304;
  const float* s1 = s0 + 2304;
  const float* s2 = omb + (size_t)(144 + g * 9 + k) * 2304;
  for (int i = threadIdx.x; i < 1728; i += 256) {
    int ch = i / 576, idx = i - ch * 576;
    const float4* src = (const float4*)(ch == 0 ? s0 : (ch == 1 ? s1 : s2));
    ((float4*)sC[ch])[idx] = src[idx];
  }
  __syncthreads();
  int dy = k / 3 - 1, dx = k % 3 - 1;
  float* o = rs + (size_t)(((b * 9 + k) * 8 + g) * 3) * 9216;
  for (int px = threadIdx.x; px < 9216; px += 256) {
    int h = px / 96, w = px - h * 96;
    float sh = fmaxf(h * 0.5f - 0.25f, 0.f);
    float sw = fmaxf(w * 0.5f - 0.25f, 0.f);
    int i0h = (int)sh; float th = sh - (float)i0h;
    int i0w = (int)sw; float tw = sw - (float)i0w;
    int i1h = min(i0h + 1, HX - 1);
    int i1w = min(i0w + 1, WX - 1);
    float r00 = (1.f - th) * (1.f - tw), r01 = (1.f - th) * tw;
    float r10 = th * (1.f - tw),         r11 = th * tw;
    int a00 = i0h * WX + i0w, a01 = i0h * WX + i1w;
    int a10 = i1h * WX + i0w, a11 = i1h * WX + i1w;
    float oy = r00 * sC[0][a00] + r01 * sC[0][a01] + r10 * sC[0][a10] + r11 * sC[0][a11];
    float ox = r00 * sC[1][a00] + r01 * sC[1][a01] + r10 * sC[1][a10] + r11 * sC[1][a11];
    float mv = r00 * sC[2][a00] + r01 * sC[2][a01] + r10 * sC[2][a10] + r11 * sC[2][a11];
    float mm = 1.f / (1.f + __expf(-mv));
    o[px]         = (float)(h + dy) + oy;
    o[9216 + px]  = (float)(w + dx) + ox;
    o[18432 + px] = mm;
  }
}

// ---------- deform K-part via MFMA, two-stage gather, per-tap LDS ----------
// NOTE: 3rd macro param must NOT be named w/x/y/z/s/d — member-access capture!
#define MAD4(d, s, mw)                                                  \
  d.x += (mw) * s.x; d.y += (mw) * s.y; d.z += (mw) * s.z; d.w += (mw) * s.w;

__global__ __launch_bounds__(256) void deform_mfma_kernel(
    const float* __restrict__ yt, const float* __restrict__ rs,
    const unsigned short* __restrict__ ap1, float* __restrict__ pt) {
  __shared__ unsigned short sval[64][72];       // 9216 B -> up to 8 blocks/CU
  int t = threadIdx.x;
  int bid = blockIdx.x;                         // 1728
  int logical = (bid & 7) * 216 + (bid >> 3);   // bijective XCD swizzle
  int p = logical / 576;
  int tile576 = logical % 576;
  int b = tile576 / 144;
  int tl = tile576 % 144;
  int h0 = (tl / 12) * 8;
  int w0 = (tl % 12) * 8;
  int k0 = p * 3;

  int pl = t & 63;               // px within 8x8 tile
  int g0 = t >> 6;               // gathers groups g0 and g0+4
  int gh = h0 + (pl >> 3);
  int gw = w0 + (pl & 7);
  int px96 = gh * WY + gw;
  const float* rsb = rs + (size_t)b * 1990656 + px96;
  const float* ytb = yt + (size_t)b * 9216 * 64;

  // ---- Stage A: all 18 rs loads -> weights + clamped offsets for 6 items ----
  float wq[6][4];
  int oq[6][4];                  // element offsets into ytb
#pragma unroll
  for (int it = 0; it < 6; ++it) {
    int tap = it >> 1;
    int g = g0 + (it & 1) * 4;
    int gc = g * 8;
    const float* r0 = rsb + (size_t)(((k0 + tap) * 8 + g) * 3) * 9216;
    float py = r0[0], pxf = r0[9216], m = r0[18432];
    float y0f = floorf(py), x0f = floorf(pxf);
    float ty = py - y0f, tx = pxf - x0f;
    int y0 = (int)y0f, x0 = (int)x0f;
    int y1 = y0 + 1, x1 = x0 + 1;
    float w00 = (1.f - ty) * (1.f - tx) * m, w01 = (1.f - ty) * tx * m;
    float w10 = ty * (1.f - tx) * m,         w11 = ty * tx * m;
    wq[it][0] = ((unsigned)y0 < HY && (unsigned)x0 < WY) ? w00 : 0.f;
    wq[it][1] = ((unsigned)y0 < HY && (unsigned)x1 < WY) ? w01 : 0.f;
    wq[it][2] = ((unsigned)y1 < HY && (unsigned)x0 < WY) ? w10 : 0.f;
    wq[it][3] = ((unsigned)y1 < HY && (unsigned)x1 < WY) ? w11 : 0.f;
    int y0c = min(max(y0, 0), HY - 1), y1c = min(max(y1, 0), HY - 1);
    int x0c = min(max(x0, 0), WY - 1), x1c = min(max(x1, 0), WY - 1);
    oq[it][0] = (y0c * WY + x0c) * 64 + gc;
    oq[it][1] = (y0c * WY + x1c) * 64 + gc;
    oq[it][2] = (y1c * WY + x0c) * 64 + gc;
    oq[it][3] = (y1c * WY + x1c) * 64 + gc;
  }

  // ---- Stage B: per tap {gather 2 items -> LDS -> MFMA} ----
  int w = t >> 6;
  int l = t & 63;
  int lr = l & 15;
  int lg = l >> 4;
  f32x4 acc[4] = {};
#pragma unroll
  for (int tap = 0; tap < 3; ++tap) {
    if (tap) __syncthreads();               // prev MFMA reads done
#pragma unroll
    for (int gg = 0; gg < 2; ++gg) {
      int it = tap * 2 + gg;
      int gc = (g0 + gg * 4) * 8;
      float4 s0 = {0, 0, 0, 0}, s1 = {0, 0, 0, 0};
#pragma unroll
      for (int c4 = 0; c4 < 4; ++c4) {
        const float* pp = ytb + oq[it][c4];
        float4 cA = *(const float4*)pp;
        float4 cB = *(const float4*)(pp + 4);
        float mw = wq[it][c4];
        MAD4(s0, cA, mw) MAD4(s1, cB, mw)
      }
      *(uint4*)&sval[pl][gc] =
          make_uint4(pk2(s0.x, s0.y), pk2(s0.z, s0.w), pk2(s1.x, s1.y), pk2(s1.z, s1.w));
    }
    __syncthreads();
#pragma unroll
    for (int half = 0; half < 2; ++half) {
      int s = tap * 2 + half;
      int c0 = half * 32;
      bf16x8 av = *(const bf16x8*)(ap1 +
          (size_t)(((p * 6 + s) * 4 + w) * 64 + l) * 8);
#pragma unroll
      for (int f = 0; f < 4; ++f) {
        bf16x8 bv = *(const bf16x8*)&sval[f * 16 + lr][c0 + lg * 8];
        acc[f] = __builtin_amdgcn_mfma_f32_16x16x32_bf16(av, bv, acc[f], 0, 0, 0);
      }
    }
  }

  float* pb = pt + (size_t)(p * 576 + tile576) * 4096;   // [oc64][px64]
#pragma unroll
  for (int f = 0; f < 4; ++f) {
#pragma unroll
    for (int i = 0; i < 4; ++i) {
      int oc = w * 16 + lg * 4 + i;
      pb[oc * 64 + f * 16 + lr] = acc[f][i];
    }
  }
}

// ---------- dreduce: sum 3 deform parts + bias + relu -> out ----------
__global__ __launch_bounds__(256) void dreduce_kernel(
    const float* __restrict__ pt, const float* __restrict__ bdc,
    float* __restrict__ out) {
  int tile = blockIdx.x;  // 0..575
  int b = tile / 144;
  int tl = tile % 144;
  int h0 = (tl / 12) * 8;
  int w0 = (tl % 12) * 8;
  int n = threadIdx.x;
  int oc = n >> 2;
  int rq = n & 3;
  const float4* p0 = (const float4*)(pt + (size_t)(0 * 576 + tile) * 4096);
  const float4* p1 = (const float4*)(pt + (size_t)(1 * 576 + tile) * 4096);
  const float4* p2 = (const float4*)(pt + (size_t)(2 * 576 + tile) * 4096);
  float bv = bdc[oc];
#pragma unroll
  for (int r = 0; r < 4; ++r) {
    int px4 = rq * 4 + r;           // 0..15 (float4 chunks of 64px)
    int j4 = oc * 16 + px4;
    int dh = px4 >> 1;
    int dw = (px4 & 1) * 4;
    float4 a = p0[j4], c = p1[j4], d = p2[j4];
    float4 o;
    o.x = fmaxf(a.x + c.x + d.x + bv, 0.f);
    o.y = fmaxf(a.y + c.y + d.y + bv, 0.f);
    o.z = fmaxf(a.z + c.z + d.z + bv, 0.f);
    o.w = fmaxf(a.w + c.w + d.w + bv, 0.f);
    *(float4*)&out[((size_t)(b * 64 + oc) * 96 + (h0 + dh)) * 96 + w0 + dw] = o;
  }
}

extern "C" void kernel_launch(void* const* d_in, const int* in_sizes, int n_in,
                              void* d_out, int out_size, void* d_ws, size_t ws_size,
                              hipStream_t stream) {
  const float* x = (const float*)d_in[0];
  const float* y = (const float*)d_in[1];
  const float* w_om = (const float*)d_in[2];
  const float* b_om = (const float*)d_in[3];
  const float* w_dc = (const float*)d_in[4];
  const float* b_dc = (const float*)d_in[5];
  float* out = (float*)d_out;

  float* om  = (float*)d_ws;                       // 1,990,656 f
  unsigned short* ap2 = (unsigned short*)(om + 1990656);   // 147,456 bf16
  unsigned short* ap1 = ap2 + 147456;              //  36,864 bf16
  float* yt  = (float*)(ap1 + 36864);              // 2,359,296 f
  float* shr = yt + 2359296;                       // 7,962,624 f (pc then rs)
  float* pc  = shr;                                // 7,077,888 f
  float* rs  = shr;                                // 7,962,624 f
  float* pt  = shr + 7962624;                      // 7,077,888 f

  prep_pack_kernel<<<720, 256, 0, stream>>>(w_om, w_dc, ap2, ap1);
  ytr_kernel<<<576, 256, 0, stream>>>(y, yt);
  conv_mfma_kernel<<<1728, 256, 0, stream>>>(x, ap2, pc);
  creduce_kernel<<<576, 256, 0, stream>>>(pc, b_om, om);
  resize_kernel<<<288, 256, 0, stream>>>(om, rs);
  deform_mfma_kernel<<<1728, 256, 0, stream>>>(yt, rs, ap1, pt);
  dreduce_kernel<<<576, 256, 0, stream>>>(pt, b_dc, out);
}

// Round 9
// 101.732 us; speedup vs baseline: 1.1778x; 1.1778x over previous
//
#include <hip/hip_runtime.h>
#include <math.h>

#define HX 48
#define WX 48
#define OMC 216
#define HY 96
#define WY 96

typedef __attribute__((ext_vector_type(8))) short bf16x8;
typedef __attribute__((ext_vector_type(4))) float f32x4;

__device__ inline unsigned short f2bf(float f) {
  unsigned u = __float_as_uint(f);
  return (unsigned short)((u + 0x7fffu + ((u >> 16) & 1u)) >> 16);  // RNE
}
__device__ inline unsigned pk2(float a, float b) {
  return (unsigned)f2bf(a) | ((unsigned)f2bf(b) << 16);
}

// ws layout (floats):
//  om  @ 0          : 1,990,656
//  ap2 @ 1,990,656  :    73,728   (147,456 bf16: conv A-frags [3p][6s][16m][64l][8])
//  ap1 @ 2,064,384  :    18,432   ( 36,864 bf16: deform A-frags [3p][6s][4w][64l][8])
//  yt  @ 2,082,816  : 2,359,296
//  rs  @ 4,442,112  : 7,962,624   ([b][k][g][px9216][3] = py,px,m interleaved)
//  total ~47.6 MiB. No partial buffers (pc/pt) anymore.

// ---------- prep: pack bf16 MFMA A-fragments for both GEMMs ----------
__global__ __launch_bounds__(256) void prep_pack_kernel(
    const float* __restrict__ w_om, const float* __restrict__ w_dc,
    unsigned short* __restrict__ ap2, unsigned short* __restrict__ ap1) {
  int idx = blockIdx.x * 256 + threadIdx.x;   // 0..184319
  if (idx < 147456) {
    int j = idx & 7;
    int tmp = idx >> 3;
    int l = tmp & 63; tmp >>= 6;
    int m = tmp & 15; tmp >>= 4;              // 0..17
    int s = tmp % 6, p = tmp / 6;
    int oc = m * 16 + (l & 15);
    int kk = s * 32 + (l >> 4) * 8 + j;       // 0..191
    int tap = kk >> 6, c = kk & 63;
    int k = p * 3 + tap;
    ap2[idx] = (oc < OMC) ? f2bf(w_om[oc * 576 + c * 9 + k]) : (unsigned short)0;
  } else {
    int i2 = idx - 147456;                    // < 36864
    int j = i2 & 7;
    int tmp = i2 >> 3;
    int l = tmp & 63; tmp >>= 6;
    int w = tmp & 3; tmp >>= 2;               // 0..17
    int s = tmp % 6, p = tmp / 6;
    int oc = w * 16 + (l & 15);
    int kk = s * 32 + (l >> 4) * 8 + j;
    int tap = kk >> 6, c = kk & 63;
    ap1[i2] = f2bf(w_dc[oc * 576 + c * 9 + p * 3 + tap]);
  }
}

// ---------- y[b][c][p] -> yt[b][p][c] (fp32) ----------
__global__ __launch_bounds__(256) void ytr_kernel(const float* __restrict__ y,
                                                  float* __restrict__ yt) {
  __shared__ float tile[64][65];
  int blk = blockIdx.x;  // 576 = 4b * 144
  int b = blk / 144;
  int p0 = (blk % 144) * 64;
  int t = threadIdx.x;
  int pl = t & 63;
  int cb = t >> 6;
#pragma unroll
  for (int i = 0; i < 16; ++i) {
    int c = cb * 16 + i;
    tile[c][pl] = y[((size_t)(b * 64 + c)) * 9216 + p0 + pl];
  }
  __syncthreads();
  int cw = t & 63;
  int pb = t >> 6;
#pragma unroll
  for (int i = 0; i < 16; ++i) {
    int p = pb * 16 + i;
    yt[((size_t)(b * 9216 + p0 + p)) * 64 + cw] = tile[cw][p];
  }
}

// ---------- conv (all 9 taps) via MFMA: 256oc x 16px -> om + bias ----------
__global__ __launch_bounds__(256) void conv_mfma_kernel(
    const float* __restrict__ x, const unsigned short* __restrict__ ap2,
    const float* __restrict__ bom, float* __restrict__ om) {
  __shared__ unsigned short sB[9][16][72];    // 20736 B, [tap][px][c]
  int t = threadIdx.x;
  int bid = blockIdx.x;                       // 576
  int logical = (bid & 7) * 72 + (bid >> 3);  // bijective XCD swizzle
  int b = logical / 144;
  int tl = logical % 144;
  int h0 = (tl / 12) * 4;
  int w0 = (tl % 12) * 4;
  int s_ic = t >> 2;
  int s_row = t & 3;
  const float* xp = x + (size_t)b * 64 * 2304 + (size_t)s_ic * 2304;

#pragma unroll
  for (int k = 0; k < 9; ++k) {
    int dy = k / 3 - 1, dx = k % 3 - 1;
    int hh = h0 + s_row + dy;
    int ww = w0 + dx;
    bool hv = (unsigned)hh < (unsigned)HX;
    int hc = min(max(hh, 0), HX - 1);
    const float* xr = xp + hc * WX;
#pragma unroll
    for (int j = 0; j < 4; ++j) {
      int wcj = min(max(ww + j, 0), WX - 1);
      float v = xr[wcj] * ((hv && (unsigned)(ww + j) < (unsigned)WX) ? 1.f : 0.f);
      sB[k][s_row * 4 + j][s_ic] = f2bf(v);
    }
  }
  __syncthreads();

  int w = t >> 6;
  int l = t & 63;
  int lr = l & 15;
  int lg = l >> 4;
  f32x4 acc[4] = {};
#pragma unroll
  for (int p = 0; p < 3; ++p) {
#pragma unroll
    for (int s = 0; s < 6; ++s) {
      int tapidx = p * 3 + (s >> 1);
      int c0 = (s & 1) * 32;
      bf16x8 bv = *(const bf16x8*)&sB[tapidx][lr][c0 + lg * 8];
#pragma unroll
      for (int m = 0; m < 4; ++m) {
        bf16x8 av = *(const bf16x8*)(ap2 +
            (size_t)((((p * 6 + s) * 16) + w * 4 + m) * 64 + l) * 8);
        acc[m] = __builtin_amdgcn_mfma_f32_16x16x32_bf16(av, bv, acc[m], 0, 0, 0);
      }
    }
  }
  // epilogue: bias + direct om store (px = lr, row-major 4x4)
  int prow = lr >> 2, pcol = lr & 3;
#pragma unroll
  for (int m = 0; m < 4; ++m) {
    int ocb = (w * 4 + m) * 16 + lg * 4;
    if (ocb < OMC) {
      float4 bb = *(const float4*)&bom[ocb];
      float bvv[4] = {bb.x, bb.y, bb.z, bb.w};
#pragma unroll
      for (int i = 0; i < 4; ++i) {
        om[((size_t)(b * OMC + ocb + i)) * 2304 + (h0 + prow) * WX + w0 + pcol] =
            acc[m][i] + bvv[i];
      }
    }
  }
}

// ---------- resize: LDS-staged, one block per (b,k,g); interleaved [px][3] ----
__global__ __launch_bounds__(256) void resize_kernel(const float* __restrict__ om,
                                                     float* __restrict__ rs) {
  __shared__ float sC[3][2304];
  int blk = blockIdx.x;         // 288 = b*72 + k*8 + g
  int g = blk % 8;
  int k = (blk / 8) % 9;
  int b = blk / 72;
  const float* omb = om + (size_t)b * OMC * 2304;
  const float* s0 = omb + (size_t)(g * 18 + k * 2) * 2304;
  const float* s1 = s0 + 2304;
  const float* s2 = omb + (size_t)(144 + g * 9 + k) * 2304;
  for (int i = threadIdx.x; i < 1728; i += 256) {
    int ch = i / 576, idx = i - ch * 576;
    const float4* src = (const float4*)(ch == 0 ? s0 : (ch == 1 ? s1 : s2));
    ((float4*)sC[ch])[idx] = src[idx];
  }
  __syncthreads();
  int dy = k / 3 - 1, dx = k % 3 - 1;
  float* o = rs + (size_t)((b * 9 + k) * 8 + g) * 9216 * 3;
  for (int px = threadIdx.x; px < 9216; px += 256) {
    int h = px / 96, w = px - h * 96;
    float sh = fmaxf(h * 0.5f - 0.25f, 0.f);
    float sw = fmaxf(w * 0.5f - 0.25f, 0.f);
    int i0h = (int)sh; float th = sh - (float)i0h;
    int i0w = (int)sw; float tw = sw - (float)i0w;
    int i1h = min(i0h + 1, HX - 1);
    int i1w = min(i0w + 1, WX - 1);
    float r00 = (1.f - th) * (1.f - tw), r01 = (1.f - th) * tw;
    float r10 = th * (1.f - tw),         r11 = th * tw;
    int a00 = i0h * WX + i0w, a01 = i0h * WX + i1w;
    int a10 = i1h * WX + i0w, a11 = i1h * WX + i1w;
    float oy = r00 * sC[0][a00] + r01 * sC[0][a01] + r10 * sC[0][a10] + r11 * sC[0][a11];
    float ox = r00 * sC[1][a00] + r01 * sC[1][a01] + r10 * sC[1][a10] + r11 * sC[1][a11];
    float mv = r00 * sC[2][a00] + r01 * sC[2][a01] + r10 * sC[2][a10] + r11 * sC[2][a11];
    float mm = 1.f / (1.f + __expf(-mv));
    o[px * 3 + 0] = (float)(h + dy) + oy;
    o[px * 3 + 1] = (float)(w + dx) + ox;
    o[px * 3 + 2] = mm;
  }
}

// ---------- deform fused: 32px x 64oc x all-9-taps, double-buffered LDS ----------
// NOTE: 3rd macro param must NOT be named w/x/y/z/s/d — member-access capture!
#define MAD4(d, s, mw)                                                  \
  d.x += (mw) * s.x; d.y += (mw) * s.y; d.z += (mw) * s.z; d.w += (mw) * s.w;

__global__ __launch_bounds__(256) void deform_mfma_kernel(
    const float* __restrict__ yt, const float* __restrict__ rs,
    const unsigned short* __restrict__ ap1, const float* __restrict__ bdc,
    float* __restrict__ out) {
  __shared__ unsigned short sval[2][32][72];    // 9216 B
  int t = threadIdx.x;
  int bid = blockIdx.x;                         // 1152
  int logical = (bid & 7) * 144 + (bid >> 3);   // bijective XCD swizzle
  int b = logical / 288;
  int tl = logical % 288;
  int h0 = (tl / 12) * 4;                       // 24 h-tiles of 4
  int w0 = (tl % 12) * 8;                       // 12 w-tiles of 8
  int px = t & 31;                              // gather item: (g, px)
  int g = t >> 5;
  int gh = h0 + (px >> 3);
  int gw = w0 + (px & 7);
  int px96 = gh * WY + gw;
  int gc = g * 8;
  const float* ytb = yt + (size_t)b * 9216 * 64;
  const float* rsb = rs + (size_t)b * 9 * 8 * 9216 * 3;

  int w = t >> 6;
  int l = t & 63;
  int lr = l & 15;
  int lg = l >> 4;

  float4 L[8];
  float wq[4];

  auto issue = [&](int tap, float4* Lo, float* wo) {
    const float* r0 = rsb + ((size_t)(tap * 8 + g) * 9216 + px96) * 3;
    float py = r0[0], pxf = r0[1], m = r0[2];
    float y0f = floorf(py), x0f = floorf(pxf);
    float ty = py - y0f, tx = pxf - x0f;
    int y0 = (int)y0f, x0 = (int)x0f;
    int y1 = y0 + 1, x1 = x0 + 1;
    float w00 = (1.f - ty) * (1.f - tx) * m, w01 = (1.f - ty) * tx * m;
    float w10 = ty * (1.f - tx) * m,         w11 = ty * tx * m;
    wo[0] = ((unsigned)y0 < HY && (unsigned)x0 < WY) ? w00 : 0.f;
    wo[1] = ((unsigned)y0 < HY && (unsigned)x1 < WY) ? w01 : 0.f;
    wo[2] = ((unsigned)y1 < HY && (unsigned)x0 < WY) ? w10 : 0.f;
    wo[3] = ((unsigned)y1 < HY && (unsigned)x1 < WY) ? w11 : 0.f;
    int y0c = min(max(y0, 0), HY - 1), y1c = min(max(y1, 0), HY - 1);
    int x0c = min(max(x0, 0), WY - 1), x1c = min(max(x1, 0), WY - 1);
    const float* p00 = ytb + (size_t)(y0c * WY + x0c) * 64 + gc;
    const float* p01 = ytb + (size_t)(y0c * WY + x1c) * 64 + gc;
    const float* p10 = ytb + (size_t)(y1c * WY + x0c) * 64 + gc;
    const float* p11 = ytb + (size_t)(y1c * WY + x1c) * 64 + gc;
    Lo[0] = *(const float4*)p00; Lo[1] = *(const float4*)(p00 + 4);
    Lo[2] = *(const float4*)p01; Lo[3] = *(const float4*)(p01 + 4);
    Lo[4] = *(const float4*)p10; Lo[5] = *(const float4*)(p10 + 4);
    Lo[6] = *(const float4*)p11; Lo[7] = *(const float4*)(p11 + 4);
  };
  auto finish = [&](const float4* Li, const float* wi, int buf) {
    float4 s0 = {0, 0, 0, 0}, s1 = {0, 0, 0, 0};
    MAD4(s0, Li[0], wi[0]) MAD4(s1, Li[1], wi[0])
    MAD4(s0, Li[2], wi[1]) MAD4(s1, Li[3], wi[1])
    MAD4(s0, Li[4], wi[2]) MAD4(s1, Li[5], wi[2])
    MAD4(s0, Li[6], wi[3]) MAD4(s1, Li[7], wi[3])
    *(uint4*)&sval[buf][px][gc] =
        make_uint4(pk2(s0.x, s0.y), pk2(s0.z, s0.w), pk2(s1.x, s1.y), pk2(s1.z, s1.w));
  };

  issue(0, L, wq);
  finish(L, wq, 0);
  __syncthreads();

  f32x4 acc[2] = {};
#pragma unroll
  for (int tp = 0; tp < 9; ++tp) {
    int buf = tp & 1;
    float4 L2[8];
    float wq2[4];
    if (tp < 8) issue(tp + 1, L2, wq2);       // loads in flight over MFMA
    int p = tp / 3;
    int sl = (tp % 3) * 2;
#pragma unroll
    for (int half = 0; half < 2; ++half) {
      int s = sl + half;
      bf16x8 av = *(const bf16x8*)(ap1 +
          (size_t)(((p * 6 + s) * 4 + w) * 64 + l) * 8);
#pragma unroll
      for (int f = 0; f < 2; ++f) {
        bf16x8 bv = *(const bf16x8*)&sval[buf][f * 16 + lr][half * 32 + lg * 8];
        acc[f] = __builtin_amdgcn_mfma_f32_16x16x32_bf16(av, bv, acc[f], 0, 0, 0);
      }
    }
    if (tp < 8) finish(L2, wq2, buf ^ 1);
    __syncthreads();
  }

  // epilogue: bias + relu + store (px = f*16+lr in 8w x 4h tile)
  float4 bb = *(const float4*)&bdc[w * 16 + lg * 4];
  float bvv[4] = {bb.x, bb.y, bb.z, bb.w};
#pragma unroll
  for (int f = 0; f < 2; ++f) {
#pragma unroll
    for (int i = 0; i < 4; ++i) {
      int oc = w * 16 + lg * 4 + i;
      int pxo = f * 16 + lr;
      out[((size_t)(b * 64 + oc) * 96 + h0 + (pxo >> 3)) * 96 + w0 + (pxo & 7)] =
          fmaxf(acc[f][i] + bvv[i], 0.f);
    }
  }
}

extern "C" void kernel_launch(void* const* d_in, const int* in_sizes, int n_in,
                              void* d_out, int out_size, void* d_ws, size_t ws_size,
                              hipStream_t stream) {
  const float* x = (const float*)d_in[0];
  const float* y = (const float*)d_in[1];
  const float* w_om = (const float*)d_in[2];
  const float* b_om = (const float*)d_in[3];
  const float* w_dc = (const float*)d_in[4];
  const float* b_dc = (const float*)d_in[5];
  float* out = (float*)d_out;

  float* om  = (float*)d_ws;                       // 1,990,656 f
  unsigned short* ap2 = (unsigned short*)(om + 1990656);   // 147,456 bf16
  unsigned short* ap1 = ap2 + 147456;              //  36,864 bf16
  float* yt  = (float*)(ap1 + 36864);              // 2,359,296 f
  float* rs  = yt + 2359296;                       // 7,962,624 f

  prep_pack_kernel<<<720, 256, 0, stream>>>(w_om, w_dc, ap2, ap1);
  ytr_kernel<<<576, 256, 0, stream>>>(y, yt);
  conv_mfma_kernel<<<576, 256, 0, stream>>>(x, ap2, b_om, om);
  resize_kernel<<<288, 256, 0, stream>>>(om, rs);
  deform_mfma_kernel<<<1152, 256, 0, stream>>>(yt, rs, ap1, b_dc, out);
}

// Round 10
// 83.746 us; speedup vs baseline: 1.4308x; 1.2148x over previous
//
#include <hip/hip_runtime.h>
#include <math.h>

#define HX 48
#define WX 48
#define OMC 216
#define HY 96
#define WY 96

typedef __attribute__((ext_vector_type(8))) short bf16x8;
typedef __attribute__((ext_vector_type(4))) float f32x4;

__device__ inline unsigned short f2bf(float f) {
  unsigned u = __float_as_uint(f);
  return (unsigned short)((u + 0x7fffu + ((u >> 16) & 1u)) >> 16);  // RNE
}
__device__ inline unsigned pk2(float a, float b) {
  return (unsigned)f2bf(a) | ((unsigned)f2bf(b) << 16);
}

// ws layout (floats):
//  om  @ 0          : 1,990,656
//  ap2 @ 1,990,656  :    73,728   (147,456 bf16: conv A-frags [3p][6s][16m][64l][8])
//  ap1 @ 2,064,384  :    18,432   ( 36,864 bf16: deform A-frags [3p][6s][4w][64l][8])
//  yt  @ 2,082,816  : 2,359,296
//  rs  @ 4,442,112  : 7,962,624   ([b][k][g][px9216][3] = py,px,m interleaved)

// ---------- fused: prep (blocks 0..719) + ytr (blocks 720..1295) ----------
__global__ __launch_bounds__(256) void prep_ytr_kernel(
    const float* __restrict__ w_om, const float* __restrict__ w_dc,
    const float* __restrict__ y,
    unsigned short* __restrict__ ap2, unsigned short* __restrict__ ap1,
    float* __restrict__ yt) {
  __shared__ float tile[64][65];
  int bid = blockIdx.x;
  int t = threadIdx.x;
  if (bid < 720) {
    int idx = bid * 256 + t;                  // 0..184319
    if (idx < 147456) {
      int j = idx & 7;
      int tmp = idx >> 3;
      int l = tmp & 63; tmp >>= 6;
      int m = tmp & 15; tmp >>= 4;            // 0..17
      int s = tmp % 6, p = tmp / 6;
      int oc = m * 16 + (l & 15);
      int kk = s * 32 + (l >> 4) * 8 + j;     // 0..191
      int tap = kk >> 6, c = kk & 63;
      int k = p * 3 + tap;
      ap2[idx] = (oc < OMC) ? f2bf(w_om[oc * 576 + c * 9 + k]) : (unsigned short)0;
    } else {
      int i2 = idx - 147456;                  // < 36864
      int j = i2 & 7;
      int tmp = i2 >> 3;
      int l = tmp & 63; tmp >>= 6;
      int w = tmp & 3; tmp >>= 2;             // 0..17
      int s = tmp % 6, p = tmp / 6;
      int oc = w * 16 + (l & 15);
      int kk = s * 32 + (l >> 4) * 8 + j;
      int tap = kk >> 6, c = kk & 63;
      ap1[i2] = f2bf(w_dc[oc * 576 + c * 9 + p * 3 + tap]);
    }
  } else {
    int blk = bid - 720;                      // 576 = 4b * 144
    int b = blk / 144;
    int p0 = (blk % 144) * 64;
    int pl = t & 63;
    int cb = t >> 6;
#pragma unroll
    for (int i = 0; i < 16; ++i) {
      int c = cb * 16 + i;
      tile[c][pl] = y[((size_t)(b * 64 + c)) * 9216 + p0 + pl];
    }
    __syncthreads();
    int cw = t & 63;
    int pb = t >> 6;
#pragma unroll
    for (int i = 0; i < 16; ++i) {
      int p = pb * 16 + i;
      yt[((size_t)(b * 9216 + p0 + p)) * 64 + cw] = tile[cw][p];
    }
  }
}

// ---------- conv (9 taps) via MFMA, oc-split: 128oc x 16px per block ----------
__global__ __launch_bounds__(256) void conv_mfma_kernel(
    const float* __restrict__ x, const unsigned short* __restrict__ ap2,
    const float* __restrict__ bom, float* __restrict__ om) {
  __shared__ unsigned short sB[9][16][72];    // 20736 B, [tap][px][c]
  int t = threadIdx.x;
  int bid = blockIdx.x;                       // 1152
  int logical = (bid & 7) * 144 + (bid >> 3); // bijective XCD swizzle
  int och = logical / 576;                    // oc half
  int rem = logical % 576;
  int b = rem / 144;
  int tl = rem % 144;
  int h0 = (tl / 12) * 4;
  int w0 = (tl % 12) * 4;
  int s_ic = t >> 2;
  int s_row = t & 3;
  const float* xp = x + (size_t)b * 64 * 2304 + (size_t)s_ic * 2304;

#pragma unroll
  for (int k = 0; k < 9; ++k) {
    int dy = k / 3 - 1, dx = k % 3 - 1;
    int hh = h0 + s_row + dy;
    int ww = w0 + dx;
    bool hv = (unsigned)hh < (unsigned)HX;
    int hc = min(max(hh, 0), HX - 1);
    const float* xr = xp + hc * WX;
#pragma unroll
    for (int j = 0; j < 4; ++j) {
      int wcj = min(max(ww + j, 0), WX - 1);
      float v = xr[wcj] * ((hv && (unsigned)(ww + j) < (unsigned)WX) ? 1.f : 0.f);
      sB[k][s_row * 4 + j][s_ic] = f2bf(v);
    }
  }
  __syncthreads();

  int w = t >> 6;
  int l = t & 63;
  int lr = l & 15;
  int lg = l >> 4;
  f32x4 acc[2] = {};
#pragma unroll
  for (int p = 0; p < 3; ++p) {
#pragma unroll
    for (int s = 0; s < 6; ++s) {
      int tapidx = p * 3 + (s >> 1);
      int c0 = (s & 1) * 32;
      bf16x8 bv = *(const bf16x8*)&sB[tapidx][lr][c0 + lg * 8];
#pragma unroll
      for (int m = 0; m < 2; ++m) {
        int mq = och * 8 + w * 2 + m;         // 0..15
        bf16x8 av = *(const bf16x8*)(ap2 +
            (size_t)((((p * 6 + s) * 16) + mq) * 64 + l) * 8);
        acc[m] = __builtin_amdgcn_mfma_f32_16x16x32_bf16(av, bv, acc[m], 0, 0, 0);
      }
    }
  }
  int prow = lr >> 2, pcol = lr & 3;
#pragma unroll
  for (int m = 0; m < 2; ++m) {
    int ocb = (och * 8 + w * 2 + m) * 16 + lg * 4;
    if (ocb < OMC) {
      float4 bb = *(const float4*)&bom[ocb];
      float bvv[4] = {bb.x, bb.y, bb.z, bb.w};
#pragma unroll
      for (int i = 0; i < 4; ++i) {
        om[((size_t)(b * OMC + ocb + i)) * 2304 + (h0 + prow) * WX + w0 + pcol] =
            acc[m][i] + bvv[i];
      }
    }
  }
}

// ---------- resize: 4-way px split, stage only 14 src rows ----------
__global__ __launch_bounds__(256) void resize_kernel(const float* __restrict__ om,
                                                     float* __restrict__ rs) {
  __shared__ float sR[3][14][48];             // 8064 B
  int bid = blockIdx.x;                       // 1152 = 288 * 4
  int q = bid & 3;
  int grp = bid >> 2;                         // 0..287 = b*72 + k*8 + g
  int g = grp % 8;
  int k = (grp / 8) % 9;
  int b = grp / 72;
  const float* omb = om + (size_t)b * OMC * 2304;
  const float* s0 = omb + (size_t)(g * 18 + k * 2) * 2304;
  const float* s1 = s0 + 2304;
  const float* s2 = omb + (size_t)(144 + g * 9 + k) * 2304;
  int base = 12 * q - 1;
  for (int i = threadIdx.x; i < 504; i += 256) {    // 3ch * 14row * 12 f4
    int ch = i / 168;
    int r = (i % 168) / 12;
    int c4 = i % 12;
    int srow = min(max(base + r, 0), HX - 1);
    const float* src = (ch == 0) ? s0 : ((ch == 1) ? s1 : s2);
    *(float4*)&sR[ch][r][c4 * 4] = *(const float4*)&src[srow * 48 + c4 * 4];
  }
  __syncthreads();
  int dy = k / 3 - 1, dx = k % 3 - 1;
  float* o = rs + (size_t)((b * 9 + k) * 8 + g) * 9216 * 3;
  for (int pxl = threadIdx.x; pxl < 2304; pxl += 256) {
    int h = q * 24 + (pxl / 96);
    int w = pxl % 96;
    float sh = fmaxf(h * 0.5f - 0.25f, 0.f);
    float sw = fmaxf(w * 0.5f - 0.25f, 0.f);
    int i0h = (int)sh; float th = sh - (float)i0h;
    int i0w = (int)sw; float tw = sw - (float)i0w;
    int i1h = min(i0h + 1, HX - 1);
    int i1w = min(i0w + 1, WX - 1);
    int l0 = i0h - base, l1 = i1h - base;
    float r00 = (1.f - th) * (1.f - tw), r01 = (1.f - th) * tw;
    float r10 = th * (1.f - tw),         r11 = th * tw;
    float oy = r00 * sR[0][l0][i0w] + r01 * sR[0][l0][i1w] +
               r10 * sR[0][l1][i0w] + r11 * sR[0][l1][i1w];
    float ox = r00 * sR[1][l0][i0w] + r01 * sR[1][l0][i1w] +
               r10 * sR[1][l1][i0w] + r11 * sR[1][l1][i1w];
    float mv = r00 * sR[2][l0][i0w] + r01 * sR[2][l0][i1w] +
               r10 * sR[2][l1][i0w] + r11 * sR[2][l1][i1w];
    float mm = 1.f / (1.f + __expf(-mv));
    int pxg = h * 96 + w;
    o[pxg * 3 + 0] = (float)(h + dy) + oy;
    o[pxg * 3 + 1] = (float)(w + dx) + ox;
    o[pxg * 3 + 2] = mm;
  }
}

// ---------- deform fused: 16px x 64oc, 9 taps, pair-split gather ----------
// NOTE: 3rd macro param must NOT be named w/x/y/z/s/d — member-access capture!
#define MAD4(d, s, mw)                                                  \
  d.x += (mw) * s.x; d.y += (mw) * s.y; d.z += (mw) * s.z; d.w += (mw) * s.w;

__global__ __launch_bounds__(256) void deform_mfma_kernel(
    const float* __restrict__ yt, const float* __restrict__ rs,
    const unsigned short* __restrict__ ap1, const float* __restrict__ bdc,
    float* __restrict__ out) {
  __shared__ unsigned short sval[2][16][72];    // 4608 B
  int t = threadIdx.x;
  int bid = blockIdx.x;                         // 2304
  int logical = (bid & 7) * 288 + (bid >> 3);   // bijective XCD swizzle
  int b = logical / 576;
  int tl = logical % 576;
  int h0 = (tl / 24) * 4;                       // 24 h-tiles of 4
  int w0 = (tl % 24) * 4;                       // 24 w-tiles of 4

  int item = t >> 1;                            // 0..127 = g*16 + px
  int g = item >> 4;
  int px = item & 15;
  int cp = t & 1;                               // channel half of the 8-ch group
  int gh = h0 + (px >> 2);
  int gw = w0 + (px & 3);
  int px96 = gh * WY + gw;
  int chb = g * 8 + cp * 4;
  const float* ytb = yt + (size_t)b * 9216 * 64;
  const float* rsb = rs + (size_t)b * 9 * 8 * 9216 * 3;

  int w = t >> 6;
  int l = t & 63;
  int lr = l & 15;
  int lg = l >> 4;

  auto issue = [&](int tap, float4* Co, float* wo) {
    const float* r0 = rsb + ((size_t)(tap * 8 + g) * 9216 + px96) * 3;
    float py = r0[0], pxf = r0[1], m = r0[2];
    float y0f = floorf(py), x0f = floorf(pxf);
    float ty = py - y0f, tx = pxf - x0f;
    int y0 = (int)y0f, x0 = (int)x0f;
    int y1 = y0 + 1, x1 = x0 + 1;
    float w00 = (1.f - ty) * (1.f - tx) * m, w01 = (1.f - ty) * tx * m;
    float w10 = ty * (1.f - tx) * m,         w11 = ty * tx * m;
    wo[0] = ((unsigned)y0 < HY && (unsigned)x0 < WY) ? w00 : 0.f;
    wo[1] = ((unsigned)y0 < HY && (unsigned)x1 < WY) ? w01 : 0.f;
    wo[2] = ((unsigned)y1 < HY && (unsigned)x0 < WY) ? w10 : 0.f;
    wo[3] = ((unsigned)y1 < HY && (unsigned)x1 < WY) ? w11 : 0.f;
    int y0c = min(max(y0, 0), HY - 1), y1c = min(max(y1, 0), HY - 1);
    int x0c = min(max(x0, 0), WY - 1), x1c = min(max(x1, 0), WY - 1);
    Co[0] = *(const float4*)(ytb + (size_t)(y0c * WY + x0c) * 64 + chb);
    Co[1] = *(const float4*)(ytb + (size_t)(y0c * WY + x1c) * 64 + chb);
    Co[2] = *(const float4*)(ytb + (size_t)(y1c * WY + x0c) * 64 + chb);
    Co[3] = *(const float4*)(ytb + (size_t)(y1c * WY + x1c) * 64 + chb);
  };
  auto finish = [&](const float4* Ci, const float* wi, int buf) {
    float4 s0 = {0, 0, 0, 0};
    MAD4(s0, Ci[0], wi[0]) MAD4(s0, Ci[1], wi[1])
    MAD4(s0, Ci[2], wi[2]) MAD4(s0, Ci[3], wi[3])
    *(uint2*)&sval[buf][px][chb] = make_uint2(pk2(s0.x, s0.y), pk2(s0.z, s0.w));
  };

  {
    float4 C0[4]; float wt0[4];
    issue(0, C0, wt0);
    finish(C0, wt0, 0);
  }
  __syncthreads();

  f32x4 acc = {};
#pragma unroll
  for (int tp = 0; tp < 9; ++tp) {
    int buf = tp & 1;
    float4 C2[4]; float wq2[4];
    if (tp < 8) issue(tp + 1, C2, wq2);        // loads in flight over MFMA
    int p = tp / 3;
    int sl = (tp % 3) * 2;
#pragma unroll
    for (int half = 0; half < 2; ++half) {
      int s = sl + half;
      bf16x8 av = *(const bf16x8*)(ap1 +
          (size_t)(((p * 6 + s) * 4 + w) * 64 + l) * 8);
      bf16x8 bv = *(const bf16x8*)&sval[buf][lr][half * 32 + lg * 8];
      acc = __builtin_amdgcn_mfma_f32_16x16x32_bf16(av, bv, acc, 0, 0, 0);
    }
    if (tp < 8) finish(C2, wq2, buf ^ 1);
    __syncthreads();
  }

  // epilogue: bias + relu + store (oc = w*16+lg*4+i, px = lr in 4x4 tile)
  float4 bb = *(const float4*)&bdc[w * 16 + lg * 4];
  float bvv[4] = {bb.x, bb.y, bb.z, bb.w};
#pragma unroll
  for (int i = 0; i < 4; ++i) {
    int oc = w * 16 + lg * 4 + i;
    out[((size_t)(b * 64 + oc) * 96 + h0 + (lr >> 2)) * 96 + w0 + (lr & 3)] =
        fmaxf(acc[i] + bvv[i], 0.f);
  }
}

extern "C" void kernel_launch(void* const* d_in, const int* in_sizes, int n_in,
                              void* d_out, int out_size, void* d_ws, size_t ws_size,
                              hipStream_t stream) {
  const float* x = (const float*)d_in[0];
  const float* y = (const float*)d_in[1];
  const float* w_om = (const float*)d_in[2];
  const float* b_om = (const float*)d_in[3];
  const float* w_dc = (const float*)d_in[4];
  const float* b_dc = (const float*)d_in[5];
  float* out = (float*)d_out;

  float* om  = (float*)d_ws;                       // 1,990,656 f
  unsigned short* ap2 = (unsigned short*)(om + 1990656);   // 147,456 bf16
  unsigned short* ap1 = ap2 + 147456;              //  36,864 bf16
  float* yt  = (float*)(ap1 + 36864);              // 2,359,296 f
  float* rs  = yt + 2359296;                       // 7,962,624 f

  prep_ytr_kernel<<<1296, 256, 0, stream>>>(w_om, w_dc, y, ap2, ap1, yt);
  conv_mfma_kernel<<<1152, 256, 0, stream>>>(x, ap2, b_om, om);
  resize_kernel<<<1152, 256, 0, stream>>>(om, rs);
  deform_mfma_kernel<<<2304, 256, 0, stream>>>(yt, rs, ap1, b_dc, out);
}